// Round 2
// baseline (589.784 us; speedup 1.0000x reference)
//
#include <hip/hip_runtime.h>
#include <stdint.h>

// attention_block: B=8, S=2048, H=1024, fp32 in/out, bf16 internal GEMMs.
// R2: softmax via Cauchy-Schwarz bound Mhat (no exp pass), XOR-swizzled LDS
// staging (kills 4-way bank conflicts), bf16 residual (xqn_f32 dropped).

#define DEVI __device__ __forceinline__

typedef __bf16 bf16x8 __attribute__((ext_vector_type(8)));
typedef float  f32x4  __attribute__((ext_vector_type(4)));

typedef __attribute__((address_space(3))) uint32_t lds_u32_t;
typedef __attribute__((address_space(1))) uint32_t glb_u32_t;

DEVI uint16_t f2bf(float f) {
  union { float f; uint32_t u; } v; v.f = f;
  uint32_t r = (v.u + 0x7fffu + ((v.u >> 16) & 1u)) >> 16;  // RNE
  return (uint16_t)r;
}
DEVI float bf2f(uint16_t b) {
  union { uint32_t u; float f; } v; v.u = ((uint32_t)b) << 16;
  return v.f;
}
DEVI float sigm(float x) { return 1.0f / (1.0f + __expf(-x)); }

DEVI void gl_lds16(const void* g, const void* lds_base) {
  __builtin_amdgcn_global_load_lds((glb_u32_t*)(uintptr_t)g,
                                   (lds_u32_t*)(uint32_t)(uintptr_t)lds_base,
                                   16, 0, 0);
}

// ---------------- core NT GEMM tile: C[128x128] += A[128xK] * B[128xK]^T ----
// XOR swizzle: LDS physical 16B-chunk q' = q ^ (row & 3) -> 2-way (free) banks.
DEVI void gemm_tile(const uint16_t* __restrict__ A, int lda,
                    const uint16_t* __restrict__ B, int ldb,
                    int K, uint16_t* sA, uint16_t* sB, f32x4 acc[4][4])
{
  const int tid  = threadIdx.x;
  const int lane = tid & 63;
  const int w    = tid >> 6;
  const int wr   = (w >> 1) * 64;
  const int wc   = (w & 1) * 64;
  const int r0   = tid >> 2;                        // staging row 0..63
  const int c0   = (((tid & 3) ^ (r0 & 3)) * 8);    // swizzled source col (elems)
  const int m16  = lane & 15;
  const int q8   = ((lane >> 4) ^ (m16 & 3)) * 8;   // swizzled read chunk (elems)

  for (int kt = 0; kt < K; kt += 32) {
    __syncthreads();
#pragma unroll
    for (int p = 0; p < 2; p++) {
      gl_lds16(A + (size_t)(p * 64 + r0) * lda + (kt + c0), sA + (p * 256 + w * 64) * 8);
      gl_lds16(B + (size_t)(p * 64 + r0) * ldb + (kt + c0), sB + (p * 256 + w * 64) * 8);
    }
    __syncthreads();
    bf16x8 af[4], bfv[4];
#pragma unroll
    for (int i = 0; i < 4; i++) {
      af[i]  = *(const bf16x8*)(sA + (wr + i * 16 + m16) * 32 + q8);
      bfv[i] = *(const bf16x8*)(sB + (wc + i * 16 + m16) * 32 + q8);
    }
#pragma unroll
    for (int mi = 0; mi < 4; mi++)
#pragma unroll
      for (int ni = 0; ni < 4; ni++)
        acc[mi][ni] = __builtin_amdgcn_mfma_f32_16x16x32_bf16(af[mi], bfv[ni], acc[mi][ni], 0, 0, 0);
  }
}

// ---------------- gate ----------------
__global__ void gate_kernel(const float* __restrict__ v_prime,
                            const float* __restrict__ v1W, const float* __restrict__ v1b,
                            const float* __restrict__ v2W, const float* __restrict__ v2b,
                            float* __restrict__ gate)
{
  const int tid = threadIdx.x, lane = tid & 63, w = tid >> 6;
  const int j = blockIdx.x * 4 + w;
  float d1 = 0.f, d2 = 0.f;
  for (int it = 0; it < 16; it++) {
    int i = it * 64 + lane;
    float vp = sigm(v_prime[i]);
    d1 += vp * v1W[(size_t)j * 1024 + i];
    d2 += vp * v2W[(size_t)j * 1024 + i];
  }
  for (int off = 32; off; off >>= 1) { d1 += __shfl_xor(d1, off); d2 += __shfl_xor(d2, off); }
  if (lane == 0) gate[j] = sigm(d1 + v1b[j]) * tanhf(d2 + v2b[j]);
}

// ---------------- fp32 -> bf16 convert (qW) ----------------
__global__ void cvt_kernel(const float* __restrict__ src, uint16_t* __restrict__ dst)
{
  size_t i = ((size_t)blockIdx.x * 256 + threadIdx.x) * 4;
  float4 v = *(const float4*)(src + i);
  *(ushort4*)(dst + i) = make_ushort4(f2bf(v.x), f2bf(v.y), f2bf(v.z), f2bf(v.w));
}

// ---------------- LayerNorm: wave-per-row; also emits max ||kr||^2 per batch
__global__ __launch_bounds__(256) void ln_kernel(
    const float* __restrict__ x,
    const float* __restrict__ qn_w, const float* __restrict__ qn_b,
    const float* __restrict__ kvn_w, const float* __restrict__ kvn_b,
    const float* __restrict__ k_prime, const float* __restrict__ gate,
    uint16_t* __restrict__ xqn_bf, uint16_t* __restrict__ kr,
    uint16_t* __restrict__ vr, int* __restrict__ krmaxsq)
{
  const int lane = threadIdx.x & 63, w = threadIdx.x >> 6;
  const int row = blockIdx.x * 4 + w;
  const float4* xr = (const float4*)(x + (size_t)row * 1024);
  float4 v[4];
  float s = 0.f, sq = 0.f;
#pragma unroll
  for (int i = 0; i < 4; i++) {
    v[i] = xr[i * 64 + lane];
    s  += v[i].x + v[i].y + v[i].z + v[i].w;
    sq += v[i].x * v[i].x + v[i].y * v[i].y + v[i].z * v[i].z + v[i].w * v[i].w;
  }
  for (int off = 32; off; off >>= 1) { s += __shfl_xor(s, off); sq += __shfl_xor(sq, off); }
  const float mean = s * (1.f / 1024.f);
  const float rstd = rsqrtf(sq * (1.f / 1024.f) - mean * mean + 1e-5f);

  float ksq = 0.f;
  const size_t o4 = (size_t)row * 256;
#pragma unroll
  for (int i = 0; i < 4; i++) {
    const int idx = i * 64 + lane;
    float4 qw = ((const float4*)qn_w)[idx],  qb4 = ((const float4*)qn_b)[idx];
    float4 kw = ((const float4*)kvn_w)[idx], kb4 = ((const float4*)kvn_b)[idx];
    float4 kp = ((const float4*)k_prime)[idx], g = ((const float4*)gate)[idx];
    float xn0 = (v[i].x - mean) * rstd, xn1 = (v[i].y - mean) * rstd;
    float xn2 = (v[i].z - mean) * rstd, xn3 = (v[i].w - mean) * rstd;
    float xq0 = xn0 * qw.x + qb4.x, xq1 = xn1 * qw.y + qb4.y;
    float xq2 = xn2 * qw.z + qb4.z, xq3 = xn3 * qw.w + qb4.w;
    float xk0 = xn0 * kw.x + kb4.x, xk1 = xn1 * kw.y + kb4.y;
    float xk2 = xn2 * kw.z + kb4.z, xk3 = xn3 * kw.w + kb4.w;
    float k0 = xk0 * sigm(kp.x), k1 = xk1 * sigm(kp.y);
    float k2 = xk2 * sigm(kp.z), k3 = xk3 * sigm(kp.w);
    ksq += k0 * k0 + k1 * k1 + k2 * k2 + k3 * k3;
    ((ushort4*)xqn_bf)[o4 + idx] = make_ushort4(f2bf(xq0), f2bf(xq1), f2bf(xq2), f2bf(xq3));
    ((ushort4*)kr)[o4 + idx] = make_ushort4(f2bf(k0), f2bf(k1), f2bf(k2), f2bf(k3));
    ((ushort4*)vr)[o4 + idx] = make_ushort4(f2bf(xk0 * g.x), f2bf(xk1 * g.y),
                                            f2bf(xk2 * g.z), f2bf(xk3 * g.w));
  }
  for (int off = 32; off; off >>= 1) ksq += __shfl_xor(ksq, off);
  if (lane == 0) atomicMax(&krmaxsq[row >> 11], __float_as_int(ksq));  // positive floats
}

// ---------------- qr GEMM: qr = (xqn @ qW^T + qb) * sig(q_prime); + row norms
__global__ __launch_bounds__(256) void qr_gemm_kernel(
    const uint16_t* __restrict__ xqn_bf, const uint16_t* __restrict__ qWbf,
    const float* __restrict__ qb, const float* __restrict__ q_prime,
    uint16_t* __restrict__ qr, float* __restrict__ qnormsq)
{
  __shared__ uint16_t sA[128 * 32], sB[128 * 32];
  f32x4 acc[4][4];
#pragma unroll
  for (int i = 0; i < 4; i++)
#pragma unroll
    for (int j = 0; j < 4; j++) acc[i][j] = (f32x4)0.0f;

  const int rowBase = blockIdx.y * 128, colBase = blockIdx.x * 128;
  gemm_tile(xqn_bf + (size_t)rowBase * 1024, 1024,
            qWbf + (size_t)colBase * 1024, 1024, 1024, sA, sB, acc);

  const int lane = threadIdx.x & 63, w = threadIdx.x >> 6;
  const int wr = (w >> 1) * 64, wc = (w & 1) * 64;
  float rsq[4][4] = {};
#pragma unroll
  for (int ni = 0; ni < 4; ni++) {
    int gc = colBase + wc + ni * 16 + (lane & 15);
    float scale = sigm(q_prime[gc]);
    float bias = qb[gc];
#pragma unroll
    for (int mi = 0; mi < 4; mi++)
#pragma unroll
      for (int r = 0; r < 4; r++) {
        int gr = rowBase + wr + mi * 16 + (lane >> 4) * 4 + r;
        float val = (acc[mi][ni][r] + bias) * scale;
        qr[(size_t)gr * 1024 + gc] = f2bf(val);
        rsq[mi][r] += val * val;
      }
  }
#pragma unroll
  for (int mi = 0; mi < 4; mi++)
#pragma unroll
    for (int r = 0; r < 4; r++) {
      float t = rsq[mi][r];
      t += __shfl_xor(t, 1); t += __shfl_xor(t, 2);
      t += __shfl_xor(t, 4); t += __shfl_xor(t, 8);
      rsq[mi][r] = t;
    }
  if ((lane & 15) == 0) {
#pragma unroll
    for (int mi = 0; mi < 4; mi++)
#pragma unroll
      for (int r = 0; r < 4; r++)
        atomicAdd(&qnormsq[rowBase + wr + mi * 16 + (lane >> 4) * 4 + r], rsq[mi][r]);
  }
}

// ---------------- bound: Mhat[b] = max||qr||*max||kr||/32 ----------------
__global__ void bound_kernel(const float* __restrict__ qnormsq,
                             const int* __restrict__ krmaxsq, float* __restrict__ MZ)
{
  const int b = blockIdx.x, tid = threadIdx.x, lane = tid & 63, w = tid >> 6;
  float m = 0.f;
  for (int i = tid; i < 2048; i += 256) m = fmaxf(m, qnormsq[b * 2048 + i]);
  for (int off = 32; off; off >>= 1) m = fmaxf(m, __shfl_xor(m, off));
  __shared__ float rm[4];
  if (lane == 0) rm[w] = m;
  __syncthreads();
  if (tid == 0) {
    float qmax = fmaxf(fmaxf(rm[0], rm[1]), fmaxf(rm[2], rm[3]));
    float kmax = __int_as_float(krmaxsq[b]);
    MZ[b] = sqrtf(qmax * kmax) * 0.03125f;   // rigorous: s <= ||q||*||k||/32
  }
}

// ---------------- transpose vr [b,t,h] -> vrt [b,h,t] (bf16) --------------
__global__ void transpose_kernel(const uint16_t* __restrict__ vr, uint16_t* __restrict__ vrt)
{
  __shared__ uint16_t t[64 * 72];
  const int b = blockIdx.z;
  const int t0 = blockIdx.x * 64, h0 = blockIdx.y * 64;
  const uint16_t* src = vr + (size_t)b * 2048 * 1024;
#pragma unroll
  for (int p = 0; p < 2; p++) {
    int flat = p * 256 + threadIdx.x;
    int r = flat >> 3, c = (flat & 7) * 8;
    *(uint4*)(&t[r * 72 + c]) = *(const uint4*)(src + (size_t)(t0 + r) * 1024 + h0 + c);
  }
  __syncthreads();
  uint16_t* dst = vrt + (size_t)b * 1024 * 2048;
#pragma unroll
  for (int p = 0; p < 2; p++) {
    int flat = p * 256 + threadIdx.x;
    int oh = flat >> 3, oc = (flat & 7) * 8;
    union { uint16_t e[8]; uint4 v; } u;
#pragma unroll
    for (int j = 0; j < 8; j++) u.e[j] = t[(oc + j) * 72 + oh];
    *(uint4*)(dst + (size_t)(h0 + oh) * 2048 + t0 + oc) = u.v;
  }
}

// ---------------- scores GEMM: writes P' = exp(s - Mhat), partial Z -------
__global__ __launch_bounds__(256) void scores_kernel(
    const uint16_t* __restrict__ qr, const uint16_t* __restrict__ kr,
    const float* __restrict__ MZ,
    uint16_t* __restrict__ scores, float* __restrict__ blockZ)
{
  __shared__ uint16_t sA[128 * 32], sB[128 * 32];
  __shared__ float redz[4];
  const int b = blockIdx.z;
  f32x4 acc[4][4];
#pragma unroll
  for (int i = 0; i < 4; i++)
#pragma unroll
    for (int j = 0; j < 4; j++) acc[i][j] = (f32x4)0.0f;

  const uint16_t* A = qr + (size_t)b * 2048 * 1024 + (size_t)blockIdx.y * 128 * 1024;
  const uint16_t* B = kr + (size_t)b * 2048 * 1024 + (size_t)blockIdx.x * 128 * 1024;
  gemm_tile(A, 1024, B, 1024, 1024, sA, sB, acc);

  const float Mhat = MZ[b];
  const int lane = threadIdx.x & 63, w = threadIdx.x >> 6;
  const int wr = (w >> 1) * 64, wc = (w & 1) * 64;
  uint16_t* S = scores + ((size_t)b << 22);
  const int rb = blockIdx.y * 128 + wr, cb = blockIdx.x * 128 + wc;

  float zt = 0.f;
#pragma unroll
  for (int mi = 0; mi < 4; mi++)
#pragma unroll
    for (int ni = 0; ni < 4; ni++)
#pragma unroll
      for (int r = 0; r < 4; r++) {
        float p = __expf(acc[mi][ni][r] * 0.03125f - Mhat);
        zt += p;
        S[(size_t)(rb + mi * 16 + (lane >> 4) * 4 + r) * 2048 + (cb + ni * 16 + (lane & 15))] = f2bf(p);
      }
  for (int off = 32; off; off >>= 1) zt += __shfl_xor(zt, off);
  if (lane == 0) redz[w] = zt;
  __syncthreads();
  if (threadIdx.x == 0) {
    int bid = (blockIdx.z * gridDim.y + blockIdx.y) * gridDim.x + blockIdx.x;
    blockZ[bid] = redz[0] + redz[1] + redz[2] + redz[3];
  }
}

// ---------------- Z reduce: per-batch sum of 256 block Z ------------------
__global__ void zreduce_kernel(const float* __restrict__ blockZ, float* __restrict__ MZ)
{
  const int b = blockIdx.x, tid = threadIdx.x, lane = tid & 63, w = tid >> 6;
  float z = blockZ[b * 256 + tid];
  for (int off = 32; off; off >>= 1) z += __shfl_xor(z, off);
  __shared__ float rz[4];
  if (lane == 0) rz[w] = z;
  __syncthreads();
  if (tid == 0) MZ[8 + b] = rz[0] + rz[1] + rz[2] + rz[3];
}

// ---------------- PV GEMM: out = P' @ vrt^T / Z + xqn (bf16 residual) -----
__global__ __launch_bounds__(256) void pv_gemm_kernel(
    const uint16_t* __restrict__ P, const uint16_t* __restrict__ vrt,
    const float* __restrict__ MZ, const uint16_t* __restrict__ xqn_bf,
    float* __restrict__ out)
{
  __shared__ uint16_t sA[128 * 32], sB[128 * 32];
  const int b = blockIdx.z;
  f32x4 acc[4][4];
#pragma unroll
  for (int i = 0; i < 4; i++)
#pragma unroll
    for (int j = 0; j < 4; j++) acc[i][j] = (f32x4)0.0f;

  const uint16_t* A = P + ((size_t)b << 22) + (size_t)blockIdx.y * 128 * 2048;
  const uint16_t* B = vrt + (size_t)b * 1024 * 2048 + (size_t)blockIdx.x * 128 * 2048;
  gemm_tile(A, 2048, B, 2048, 2048, sA, sB, acc);

  const float invZ = 1.0f / MZ[8 + b];
  const int lane = threadIdx.x & 63, w = threadIdx.x >> 6;
  const int wr = (w >> 1) * 64, wc = (w & 1) * 64;
  const int rb = blockIdx.y * 128 + wr, cb = blockIdx.x * 128 + wc;
#pragma unroll
  for (int mi = 0; mi < 4; mi++)
#pragma unroll
    for (int ni = 0; ni < 4; ni++)
#pragma unroll
      for (int r = 0; r < 4; r++) {
        int gr = rb + mi * 16 + (lane >> 4) * 4 + r;
        int gc = cb + ni * 16 + (lane & 15);
        size_t o = ((size_t)b * 2048 + gr) * 1024 + gc;
        out[o] = acc[mi][ni][r] * invZ + bf2f(xqn_bf[o]);
      }
}

extern "C" void kernel_launch(void* const* d_in, const int* in_sizes, int n_in,
                              void* d_out, int out_size, void* d_ws, size_t ws_size,
                              hipStream_t stream) {
  const float* x       = (const float*)d_in[0];
  const float* qn_w    = (const float*)d_in[1];
  const float* qn_b    = (const float*)d_in[2];
  const float* kvn_w   = (const float*)d_in[3];
  const float* kvn_b   = (const float*)d_in[4];
  const float* q_prime = (const float*)d_in[5];
  const float* k_prime = (const float*)d_in[6];
  const float* v_prime = (const float*)d_in[7];
  const float* qW      = (const float*)d_in[8];
  const float* qb      = (const float*)d_in[9];
  const float* v1W     = (const float*)d_in[10];
  const float* v1b     = (const float*)d_in[11];
  const float* v2W     = (const float*)d_in[12];
  const float* v2b     = (const float*)d_in[13];
  float* out = (float*)d_out;

  const size_t BS = 16384, H = 1024;
  char* ws = (char*)d_ws;
  size_t off = 0;
  auto alloc = [&](size_t bytes) -> char* {
    char* p = ws + off;
    off = (off + bytes + 255) & ~(size_t)255;
    return p;
  };
  float*    gate    = (float*)alloc(H * 4);
  float*    MZ      = (float*)alloc(16 * 4);        // [0..7]=Mhat, [8..15]=Z
  float*    blockZ  = (float*)alloc(2048 * 4);
  float*    qnormsq = (float*)alloc((16384 + 64) * 4);  // +krmaxsq tail
  int*      krmaxsq = (int*)(qnormsq + 16384);
  uint16_t* qWbf    = (uint16_t*)alloc(H * H * 2);
  uint16_t* xqn_bf  = (uint16_t*)alloc(BS * H * 2);     // lives to the end
  uint16_t* kr      = (uint16_t*)alloc(BS * H * 2);
  // region: [vr | spare] reused as scores (64 MB) after transpose consumes vr
  char*     regionC = alloc(BS * H * 2 * 2);
  uint16_t* vr      = (uint16_t*)regionC;
  uint16_t* scores  = (uint16_t*)regionC;
  uint16_t* vrt     = (uint16_t*)alloc(BS * H * 2);
  uint16_t* qr      = (uint16_t*)alloc(BS * H * 2);

  hipMemsetAsync(qnormsq, 0, (16384 + 64) * 4, stream);
  gate_kernel<<<256, 256, 0, stream>>>(v_prime, v1W, v1b, v2W, v2b, gate);
  cvt_kernel<<<1024, 256, 0, stream>>>(qW, qWbf);
  ln_kernel<<<4096, 256, 0, stream>>>(x, qn_w, qn_b, kvn_w, kvn_b, k_prime, gate,
                                      xqn_bf, kr, vr, krmaxsq);
  qr_gemm_kernel<<<dim3(8, 128), 256, 0, stream>>>(xqn_bf, qWbf, qb, q_prime, qr, qnormsq);
  transpose_kernel<<<dim3(32, 16, 8), 256, 0, stream>>>(vr, vrt);
  bound_kernel<<<8, 256, 0, stream>>>(qnormsq, krmaxsq, MZ);
  // vr dead; scores may overwrite region C
  scores_kernel<<<dim3(16, 16, 8), 256, 0, stream>>>(qr, kr, MZ, scores, blockZ);
  zreduce_kernel<<<8, 256, 0, stream>>>(blockZ, MZ);
  pv_gemm_kernel<<<dim3(8, 16, 8), 256, 0, stream>>>(scores, vrt, MZ, xqn_bf, out);
}

// Round 3
// 435.437 us; speedup vs baseline: 1.3545x; 1.3545x over previous
//
#include <hip/hip_runtime.h>
#include <stdint.h>

// attention_block: B=8, S=2048, H=1024, fp32 in/out, bf16 internal GEMMs.
// R3: fix ln_kernel atomic contention (atomicMax on 8 addrs -> per-row store
// + reduce in bound_kernel). Keeps R2's Mhat-bound softmax + XOR LDS swizzle.

#define DEVI __device__ __forceinline__

typedef __bf16 bf16x8 __attribute__((ext_vector_type(8)));
typedef float  f32x4  __attribute__((ext_vector_type(4)));

typedef __attribute__((address_space(3))) uint32_t lds_u32_t;
typedef __attribute__((address_space(1))) uint32_t glb_u32_t;

DEVI uint16_t f2bf(float f) {
  union { float f; uint32_t u; } v; v.f = f;
  uint32_t r = (v.u + 0x7fffu + ((v.u >> 16) & 1u)) >> 16;  // RNE
  return (uint16_t)r;
}
DEVI float bf2f(uint16_t b) {
  union { uint32_t u; float f; } v; v.u = ((uint32_t)b) << 16;
  return v.f;
}
DEVI float sigm(float x) { return 1.0f / (1.0f + __expf(-x)); }

DEVI void gl_lds16(const void* g, const void* lds_base) {
  __builtin_amdgcn_global_load_lds((glb_u32_t*)(uintptr_t)g,
                                   (lds_u32_t*)(uint32_t)(uintptr_t)lds_base,
                                   16, 0, 0);
}

// ---------------- core NT GEMM tile: C[128x128] += A[128xK] * B[128xK]^T ----
// XOR swizzle: LDS physical 16B-chunk q' = q ^ (row & 3) -> 2-way (free) banks.
DEVI void gemm_tile(const uint16_t* __restrict__ A, int lda,
                    const uint16_t* __restrict__ B, int ldb,
                    int K, uint16_t* sA, uint16_t* sB, f32x4 acc[4][4])
{
  const int tid  = threadIdx.x;
  const int lane = tid & 63;
  const int w    = tid >> 6;
  const int wr   = (w >> 1) * 64;
  const int wc   = (w & 1) * 64;
  const int r0   = tid >> 2;                        // staging row 0..63
  const int c0   = (((tid & 3) ^ (r0 & 3)) * 8);    // swizzled source col (elems)
  const int m16  = lane & 15;
  const int q8   = ((lane >> 4) ^ (m16 & 3)) * 8;   // swizzled read chunk (elems)

  for (int kt = 0; kt < K; kt += 32) {
    __syncthreads();
#pragma unroll
    for (int p = 0; p < 2; p++) {
      gl_lds16(A + (size_t)(p * 64 + r0) * lda + (kt + c0), sA + (p * 256 + w * 64) * 8);
      gl_lds16(B + (size_t)(p * 64 + r0) * ldb + (kt + c0), sB + (p * 256 + w * 64) * 8);
    }
    __syncthreads();
    bf16x8 af[4], bfv[4];
#pragma unroll
    for (int i = 0; i < 4; i++) {
      af[i]  = *(const bf16x8*)(sA + (wr + i * 16 + m16) * 32 + q8);
      bfv[i] = *(const bf16x8*)(sB + (wc + i * 16 + m16) * 32 + q8);
    }
#pragma unroll
    for (int mi = 0; mi < 4; mi++)
#pragma unroll
      for (int ni = 0; ni < 4; ni++)
        acc[mi][ni] = __builtin_amdgcn_mfma_f32_16x16x32_bf16(af[mi], bfv[ni], acc[mi][ni], 0, 0, 0);
  }
}

// ---------------- gate ----------------
__global__ void gate_kernel(const float* __restrict__ v_prime,
                            const float* __restrict__ v1W, const float* __restrict__ v1b,
                            const float* __restrict__ v2W, const float* __restrict__ v2b,
                            float* __restrict__ gate)
{
  const int tid = threadIdx.x, lane = tid & 63, w = tid >> 6;
  const int j = blockIdx.x * 4 + w;
  float d1 = 0.f, d2 = 0.f;
  for (int it = 0; it < 16; it++) {
    int i = it * 64 + lane;
    float vp = sigm(v_prime[i]);
    d1 += vp * v1W[(size_t)j * 1024 + i];
    d2 += vp * v2W[(size_t)j * 1024 + i];
  }
  for (int off = 32; off; off >>= 1) { d1 += __shfl_xor(d1, off); d2 += __shfl_xor(d2, off); }
  if (lane == 0) gate[j] = sigm(d1 + v1b[j]) * tanhf(d2 + v2b[j]);
}

// ---------------- fp32 -> bf16 convert (qW) ----------------
__global__ void cvt_kernel(const float* __restrict__ src, uint16_t* __restrict__ dst)
{
  size_t i = ((size_t)blockIdx.x * 256 + threadIdx.x) * 4;
  float4 v = *(const float4*)(src + i);
  *(ushort4*)(dst + i) = make_ushort4(f2bf(v.x), f2bf(v.y), f2bf(v.z), f2bf(v.w));
}

// ---------------- LayerNorm: wave-per-row; per-row ||kr||^2 store (no atomics)
__global__ __launch_bounds__(256) void ln_kernel(
    const float* __restrict__ x,
    const float* __restrict__ qn_w, const float* __restrict__ qn_b,
    const float* __restrict__ kvn_w, const float* __restrict__ kvn_b,
    const float* __restrict__ k_prime, const float* __restrict__ gate,
    uint16_t* __restrict__ xqn_bf, uint16_t* __restrict__ kr,
    uint16_t* __restrict__ vr, float* __restrict__ krowsq)
{
  const int lane = threadIdx.x & 63, w = threadIdx.x >> 6;
  const int row = blockIdx.x * 4 + w;
  const float4* xr = (const float4*)(x + (size_t)row * 1024);
  float4 v[4];
  float s = 0.f, sq = 0.f;
#pragma unroll
  for (int i = 0; i < 4; i++) {
    v[i] = xr[i * 64 + lane];
    s  += v[i].x + v[i].y + v[i].z + v[i].w;
    sq += v[i].x * v[i].x + v[i].y * v[i].y + v[i].z * v[i].z + v[i].w * v[i].w;
  }
  for (int off = 32; off; off >>= 1) { s += __shfl_xor(s, off); sq += __shfl_xor(sq, off); }
  const float mean = s * (1.f / 1024.f);
  const float rstd = rsqrtf(sq * (1.f / 1024.f) - mean * mean + 1e-5f);

  float ksq = 0.f;
  const size_t o4 = (size_t)row * 256;
#pragma unroll
  for (int i = 0; i < 4; i++) {
    const int idx = i * 64 + lane;
    float4 qw = ((const float4*)qn_w)[idx],  qb4 = ((const float4*)qn_b)[idx];
    float4 kw = ((const float4*)kvn_w)[idx], kb4 = ((const float4*)kvn_b)[idx];
    float4 kp = ((const float4*)k_prime)[idx], g = ((const float4*)gate)[idx];
    float xn0 = (v[i].x - mean) * rstd, xn1 = (v[i].y - mean) * rstd;
    float xn2 = (v[i].z - mean) * rstd, xn3 = (v[i].w - mean) * rstd;
    float xq0 = xn0 * qw.x + qb4.x, xq1 = xn1 * qw.y + qb4.y;
    float xq2 = xn2 * qw.z + qb4.z, xq3 = xn3 * qw.w + qb4.w;
    float xk0 = xn0 * kw.x + kb4.x, xk1 = xn1 * kw.y + kb4.y;
    float xk2 = xn2 * kw.z + kb4.z, xk3 = xn3 * kw.w + kb4.w;
    float k0 = xk0 * sigm(kp.x), k1 = xk1 * sigm(kp.y);
    float k2 = xk2 * sigm(kp.z), k3 = xk3 * sigm(kp.w);
    ksq += k0 * k0 + k1 * k1 + k2 * k2 + k3 * k3;
    ((ushort4*)xqn_bf)[o4 + idx] = make_ushort4(f2bf(xq0), f2bf(xq1), f2bf(xq2), f2bf(xq3));
    ((ushort4*)kr)[o4 + idx] = make_ushort4(f2bf(k0), f2bf(k1), f2bf(k2), f2bf(k3));
    ((ushort4*)vr)[o4 + idx] = make_ushort4(f2bf(xk0 * g.x), f2bf(xk1 * g.y),
                                            f2bf(xk2 * g.z), f2bf(xk3 * g.w));
  }
  for (int off = 32; off; off >>= 1) ksq += __shfl_xor(ksq, off);
  if (lane == 0) krowsq[row] = ksq;   // contention-free per-row store
}

// ---------------- qr GEMM: qr = (xqn @ qW^T + qb) * sig(q_prime); + row norms
__global__ __launch_bounds__(256) void qr_gemm_kernel(
    const uint16_t* __restrict__ xqn_bf, const uint16_t* __restrict__ qWbf,
    const float* __restrict__ qb, const float* __restrict__ q_prime,
    uint16_t* __restrict__ qr, float* __restrict__ qnormsq)
{
  __shared__ uint16_t sA[128 * 32], sB[128 * 32];
  f32x4 acc[4][4];
#pragma unroll
  for (int i = 0; i < 4; i++)
#pragma unroll
    for (int j = 0; j < 4; j++) acc[i][j] = (f32x4)0.0f;

  const int rowBase = blockIdx.y * 128, colBase = blockIdx.x * 128;
  gemm_tile(xqn_bf + (size_t)rowBase * 1024, 1024,
            qWbf + (size_t)colBase * 1024, 1024, 1024, sA, sB, acc);

  const int lane = threadIdx.x & 63, w = threadIdx.x >> 6;
  const int wr = (w >> 1) * 64, wc = (w & 1) * 64;
  float rsq[4][4] = {};
#pragma unroll
  for (int ni = 0; ni < 4; ni++) {
    int gc = colBase + wc + ni * 16 + (lane & 15);
    float scale = sigm(q_prime[gc]);
    float bias = qb[gc];
#pragma unroll
    for (int mi = 0; mi < 4; mi++)
#pragma unroll
      for (int r = 0; r < 4; r++) {
        int gr = rowBase + wr + mi * 16 + (lane >> 4) * 4 + r;
        float val = (acc[mi][ni][r] + bias) * scale;
        qr[(size_t)gr * 1024 + gc] = f2bf(val);
        rsq[mi][r] += val * val;
      }
  }
#pragma unroll
  for (int mi = 0; mi < 4; mi++)
#pragma unroll
    for (int r = 0; r < 4; r++) {
      float t = rsq[mi][r];
      t += __shfl_xor(t, 1); t += __shfl_xor(t, 2);
      t += __shfl_xor(t, 4); t += __shfl_xor(t, 8);
      rsq[mi][r] = t;
    }
  if ((lane & 15) == 0) {
#pragma unroll
    for (int mi = 0; mi < 4; mi++)
#pragma unroll
      for (int r = 0; r < 4; r++)
        atomicAdd(&qnormsq[rowBase + wr + mi * 16 + (lane >> 4) * 4 + r], rsq[mi][r]);
  }
}

// ---------------- bound: Mhat[b] = max||qr|| * max||kr|| / 32 -------------
__global__ void bound_kernel(const float* __restrict__ qnormsq,
                             const float* __restrict__ krowsq, float* __restrict__ MZ)
{
  const int b = blockIdx.x, tid = threadIdx.x, lane = tid & 63, w = tid >> 6;
  float mq = 0.f, mk = 0.f;
  for (int i = tid; i < 2048; i += 256) {
    mq = fmaxf(mq, qnormsq[b * 2048 + i]);
    mk = fmaxf(mk, krowsq[b * 2048 + i]);
  }
  for (int off = 32; off; off >>= 1) {
    mq = fmaxf(mq, __shfl_xor(mq, off));
    mk = fmaxf(mk, __shfl_xor(mk, off));
  }
  __shared__ float rm[4], rk[4];
  if (lane == 0) { rm[w] = mq; rk[w] = mk; }
  __syncthreads();
  if (tid == 0) {
    float qmax = fmaxf(fmaxf(rm[0], rm[1]), fmaxf(rm[2], rm[3]));
    float kmax = fmaxf(fmaxf(rk[0], rk[1]), fmaxf(rk[2], rk[3]));
    MZ[b] = sqrtf(qmax * kmax) * 0.03125f;   // rigorous: s <= ||q||*||k||/32
  }
}

// ---------------- transpose vr [b,t,h] -> vrt [b,h,t] (bf16) --------------
__global__ void transpose_kernel(const uint16_t* __restrict__ vr, uint16_t* __restrict__ vrt)
{
  __shared__ uint16_t t[64 * 72];
  const int b = blockIdx.z;
  const int t0 = blockIdx.x * 64, h0 = blockIdx.y * 64;
  const uint16_t* src = vr + (size_t)b * 2048 * 1024;
#pragma unroll
  for (int p = 0; p < 2; p++) {
    int flat = p * 256 + threadIdx.x;
    int r = flat >> 3, c = (flat & 7) * 8;
    *(uint4*)(&t[r * 72 + c]) = *(const uint4*)(src + (size_t)(t0 + r) * 1024 + h0 + c);
  }
  __syncthreads();
  uint16_t* dst = vrt + (size_t)b * 1024 * 2048;
#pragma unroll
  for (int p = 0; p < 2; p++) {
    int flat = p * 256 + threadIdx.x;
    int oh = flat >> 3, oc = (flat & 7) * 8;
    union { uint16_t e[8]; uint4 v; } u;
#pragma unroll
    for (int j = 0; j < 8; j++) u.e[j] = t[(oc + j) * 72 + oh];
    *(uint4*)(dst + (size_t)(h0 + oh) * 2048 + t0 + oc) = u.v;
  }
}

// ---------------- scores GEMM: writes P' = exp(s - Mhat), partial Z -------
__global__ __launch_bounds__(256) void scores_kernel(
    const uint16_t* __restrict__ qr, const uint16_t* __restrict__ kr,
    const float* __restrict__ MZ,
    uint16_t* __restrict__ scores, float* __restrict__ blockZ)
{
  __shared__ uint16_t sA[128 * 32], sB[128 * 32];
  __shared__ float redz[4];
  const int b = blockIdx.z;
  f32x4 acc[4][4];
#pragma unroll
  for (int i = 0; i < 4; i++)
#pragma unroll
    for (int j = 0; j < 4; j++) acc[i][j] = (f32x4)0.0f;

  const uint16_t* A = qr + (size_t)b * 2048 * 1024 + (size_t)blockIdx.y * 128 * 1024;
  const uint16_t* B = kr + (size_t)b * 2048 * 1024 + (size_t)blockIdx.x * 128 * 1024;
  gemm_tile(A, 1024, B, 1024, 1024, sA, sB, acc);

  const float Mhat = MZ[b];
  const int lane = threadIdx.x & 63, w = threadIdx.x >> 6;
  const int wr = (w >> 1) * 64, wc = (w & 1) * 64;
  uint16_t* S = scores + ((size_t)b << 22);
  const int rb = blockIdx.y * 128 + wr, cb = blockIdx.x * 128 + wc;

  float zt = 0.f;
#pragma unroll
  for (int mi = 0; mi < 4; mi++)
#pragma unroll
    for (int ni = 0; ni < 4; ni++)
#pragma unroll
      for (int r = 0; r < 4; r++) {
        float p = __expf(acc[mi][ni][r] * 0.03125f - Mhat);
        zt += p;
        S[(size_t)(rb + mi * 16 + (lane >> 4) * 4 + r) * 2048 + (cb + ni * 16 + (lane & 15))] = f2bf(p);
      }
  for (int off = 32; off; off >>= 1) zt += __shfl_xor(zt, off);
  if (lane == 0) redz[w] = zt;
  __syncthreads();
  if (threadIdx.x == 0) {
    int bid = (blockIdx.z * gridDim.y + blockIdx.y) * gridDim.x + blockIdx.x;
    blockZ[bid] = redz[0] + redz[1] + redz[2] + redz[3];
  }
}

// ---------------- Z reduce: per-batch sum of 256 block Z ------------------
__global__ void zreduce_kernel(const float* __restrict__ blockZ, float* __restrict__ MZ)
{
  const int b = blockIdx.x, tid = threadIdx.x, lane = tid & 63, w = tid >> 6;
  float z = blockZ[b * 256 + tid];
  for (int off = 32; off; off >>= 1) z += __shfl_xor(z, off);
  __shared__ float rz[4];
  if (lane == 0) rz[w] = z;
  __syncthreads();
  if (tid == 0) MZ[8 + b] = rz[0] + rz[1] + rz[2] + rz[3];
}

// ---------------- PV GEMM: out = P' @ vrt^T / Z + xqn (bf16 residual) -----
__global__ __launch_bounds__(256) void pv_gemm_kernel(
    const uint16_t* __restrict__ P, const uint16_t* __restrict__ vrt,
    const float* __restrict__ MZ, const uint16_t* __restrict__ xqn_bf,
    float* __restrict__ out)
{
  __shared__ uint16_t sA[128 * 32], sB[128 * 32];
  const int b = blockIdx.z;
  f32x4 acc[4][4];
#pragma unroll
  for (int i = 0; i < 4; i++)
#pragma unroll
    for (int j = 0; j < 4; j++) acc[i][j] = (f32x4)0.0f;

  const uint16_t* A = P + ((size_t)b << 22) + (size_t)blockIdx.y * 128 * 2048;
  const uint16_t* B = vrt + (size_t)b * 1024 * 2048 + (size_t)blockIdx.x * 128 * 2048;
  gemm_tile(A, 2048, B, 2048, 2048, sA, sB, acc);

  const float invZ = 1.0f / MZ[8 + b];
  const int lane = threadIdx.x & 63, w = threadIdx.x >> 6;
  const int wr = (w >> 1) * 64, wc = (w & 1) * 64;
  const int rb = blockIdx.y * 128 + wr, cb = blockIdx.x * 128 + wc;
#pragma unroll
  for (int mi = 0; mi < 4; mi++)
#pragma unroll
    for (int ni = 0; ni < 4; ni++)
#pragma unroll
      for (int r = 0; r < 4; r++) {
        int gr = rb + mi * 16 + (lane >> 4) * 4 + r;
        int gc = cb + ni * 16 + (lane & 15);
        size_t o = ((size_t)b * 2048 + gr) * 1024 + gc;
        out[o] = acc[mi][ni][r] * invZ + bf2f(xqn_bf[o]);
      }
}

extern "C" void kernel_launch(void* const* d_in, const int* in_sizes, int n_in,
                              void* d_out, int out_size, void* d_ws, size_t ws_size,
                              hipStream_t stream) {
  const float* x       = (const float*)d_in[0];
  const float* qn_w    = (const float*)d_in[1];
  const float* qn_b    = (const float*)d_in[2];
  const float* kvn_w   = (const float*)d_in[3];
  const float* kvn_b   = (const float*)d_in[4];
  const float* q_prime = (const float*)d_in[5];
  const float* k_prime = (const float*)d_in[6];
  const float* v_prime = (const float*)d_in[7];
  const float* qW      = (const float*)d_in[8];
  const float* qb      = (const float*)d_in[9];
  const float* v1W     = (const float*)d_in[10];
  const float* v1b     = (const float*)d_in[11];
  const float* v2W     = (const float*)d_in[12];
  const float* v2b     = (const float*)d_in[13];
  float* out = (float*)d_out;

  const size_t BS = 16384, H = 1024;
  char* ws = (char*)d_ws;
  size_t off = 0;
  auto alloc = [&](size_t bytes) -> char* {
    char* p = ws + off;
    off = (off + bytes + 255) & ~(size_t)255;
    return p;
  };
  float*    gate    = (float*)alloc(H * 4);
  float*    MZ      = (float*)alloc(16 * 4);        // [0..7]=Mhat, [8..15]=Z
  float*    blockZ  = (float*)alloc(2048 * 4);
  float*    qnormsq = (float*)alloc(16384 * 4);     // atomicAdd target (memset)
  float*    krowsq  = (float*)alloc(16384 * 4);     // plain per-row stores
  uint16_t* qWbf    = (uint16_t*)alloc(H * H * 2);
  uint16_t* xqn_bf  = (uint16_t*)alloc(BS * H * 2);     // lives to the end
  uint16_t* kr      = (uint16_t*)alloc(BS * H * 2);
  // region: [vr | spare] reused as scores (64 MB) after transpose consumes vr
  char*     regionC = alloc(BS * H * 2 * 2);
  uint16_t* vr      = (uint16_t*)regionC;
  uint16_t* scores  = (uint16_t*)regionC;
  uint16_t* vrt     = (uint16_t*)alloc(BS * H * 2);
  uint16_t* qr      = (uint16_t*)alloc(BS * H * 2);

  hipMemsetAsync(qnormsq, 0, 16384 * 4, stream);
  gate_kernel<<<256, 256, 0, stream>>>(v_prime, v1W, v1b, v2W, v2b, gate);
  cvt_kernel<<<1024, 256, 0, stream>>>(qW, qWbf);
  ln_kernel<<<4096, 256, 0, stream>>>(x, qn_w, qn_b, kvn_w, kvn_b, k_prime, gate,
                                      xqn_bf, kr, vr, krowsq);
  qr_gemm_kernel<<<dim3(8, 128), 256, 0, stream>>>(xqn_bf, qWbf, qb, q_prime, qr, qnormsq);
  transpose_kernel<<<dim3(32, 16, 8), 256, 0, stream>>>(vr, vrt);
  bound_kernel<<<8, 256, 0, stream>>>(qnormsq, krowsq, MZ);
  // vr dead; scores may overwrite region C
  scores_kernel<<<dim3(16, 16, 8), 256, 0, stream>>>(qr, kr, MZ, scores, blockZ);
  zreduce_kernel<<<8, 256, 0, stream>>>(blockZ, MZ);
  pv_gemm_kernel<<<dim3(8, 16, 8), 256, 0, stream>>>(scores, vrt, MZ, xqn_bf, out);
}

// Round 4
// 395.792 us; speedup vs baseline: 1.4901x; 1.1002x over previous
//
#include <hip/hip_runtime.h>
#include <stdint.h>

// attention_block: B=8, S=2048, H=1024, fp32 in/out, bf16 internal GEMMs.
// R4: BK=64 K-loop (32 MFMA/barrier-pair, XOR chunk swizzle for banks),
// XCD-aware grid swizzle on scores/pv (A-tile L2 reuse), vr eliminated
// (vrt = kr * gate/sigm(k') in transpose). Keeps Mhat-bound softmax.

#define DEVI __device__ __forceinline__

typedef __bf16 bf16x8 __attribute__((ext_vector_type(8)));
typedef float  f32x4  __attribute__((ext_vector_type(4)));

typedef __attribute__((address_space(3))) uint32_t lds_u32_t;
typedef __attribute__((address_space(1))) uint32_t glb_u32_t;

DEVI uint16_t f2bf(float f) {
  union { float f; uint32_t u; } v; v.f = f;
  uint32_t r = (v.u + 0x7fffu + ((v.u >> 16) & 1u)) >> 16;  // RNE
  return (uint16_t)r;
}
DEVI float bf2f(uint16_t b) {
  union { uint32_t u; float f; } v; v.u = ((uint32_t)b) << 16;
  return v.f;
}
DEVI float sigm(float x) { return 1.0f / (1.0f + __expf(-x)); }

DEVI void gl_lds16(const void* g, const void* lds_base) {
  __builtin_amdgcn_global_load_lds((glb_u32_t*)(uintptr_t)g,
                                   (lds_u32_t*)(uint32_t)(uintptr_t)lds_base,
                                   16, 0, 0);
}

// ---- core NT GEMM tile, BK=64: C[128x128] += A[128xK] * B[128xK]^T --------
// LDS row = 64 elems = 128 B. Without swizzle all lanes of a b128 frag-read
// would hit 16 of 32 banks (row stride = bank wrap). XOR the 16B-chunk index
// with (row&7): staging source col c0 = ((tid&7)^(r0&7))*8 puts logical chunk
// (c^(r&7)) at phys chunk c; frag reads apply the same XOR. All 32 banks, 2-way.
DEVI void gemm_tile(const uint16_t* __restrict__ A, int lda,
                    const uint16_t* __restrict__ B, int ldb,
                    int K, uint16_t* sA, uint16_t* sB, f32x4 acc[4][4])
{
  const int tid  = threadIdx.x;
  const int lane = tid & 63;
  const int w    = tid >> 6;
  const int wr   = (w >> 1) * 64;
  const int wc   = (w & 1) * 64;
  const int r0   = tid >> 3;                           // staging row 0..31
  const int c0   = (((tid & 7) ^ (r0 & 7)) * 8);       // swizzled source col
  const int m16  = lane & 15;
  const int quad = lane >> 4;

  for (int kt = 0; kt < K; kt += 64) {
    __syncthreads();
#pragma unroll
    for (int p = 0; p < 4; p++) {
      gl_lds16(A + (size_t)(p * 32 + r0) * lda + (kt + c0), sA + (p * 32 + w * 8) * 64);
      gl_lds16(B + (size_t)(p * 32 + r0) * ldb + (kt + c0), sB + (p * 32 + w * 8) * 64);
    }
    __syncthreads();
#pragma unroll
    for (int s = 0; s < 2; s++) {
      bf16x8 af[4], bfv[4];
#pragma unroll
      for (int i = 0; i < 4; i++) {
        const int chA = ((s * 4 + quad) ^ (m16 & 7)) * 8;
        af[i]  = *(const bf16x8*)(sA + (wr + i * 16 + m16) * 64 + chA);
        bfv[i] = *(const bf16x8*)(sB + (wc + i * 16 + m16) * 64 + chA);
      }
#pragma unroll
      for (int mi = 0; mi < 4; mi++)
#pragma unroll
        for (int ni = 0; ni < 4; ni++)
          acc[mi][ni] = __builtin_amdgcn_mfma_f32_16x16x32_bf16(af[mi], bfv[ni], acc[mi][ni], 0, 0, 0);
    }
  }
}

// ---------------- gate: gate2[j] = sig(.)·tanh(.) / sig(k'[j]) ------------
__global__ void gate_kernel(const float* __restrict__ v_prime,
                            const float* __restrict__ v1W, const float* __restrict__ v1b,
                            const float* __restrict__ v2W, const float* __restrict__ v2b,
                            const float* __restrict__ k_prime,
                            float* __restrict__ gate2)
{
  const int tid = threadIdx.x, lane = tid & 63, w = tid >> 6;
  const int j = blockIdx.x * 4 + w;
  float d1 = 0.f, d2 = 0.f;
  for (int it = 0; it < 16; it++) {
    int i = it * 64 + lane;
    float vp = sigm(v_prime[i]);
    d1 += vp * v1W[(size_t)j * 1024 + i];
    d2 += vp * v2W[(size_t)j * 1024 + i];
  }
  for (int off = 32; off; off >>= 1) { d1 += __shfl_xor(d1, off); d2 += __shfl_xor(d2, off); }
  if (lane == 0)
    gate2[j] = sigm(d1 + v1b[j]) * tanhf(d2 + v2b[j]) / sigm(k_prime[j]);
}

// ---------------- fp32 -> bf16 convert (qW) ----------------
__global__ void cvt_kernel(const float* __restrict__ src, uint16_t* __restrict__ dst)
{
  size_t i = ((size_t)blockIdx.x * 256 + threadIdx.x) * 4;
  float4 v = *(const float4*)(src + i);
  *(ushort4*)(dst + i) = make_ushort4(f2bf(v.x), f2bf(v.y), f2bf(v.z), f2bf(v.w));
}

// ---------------- LayerNorm: wave-per-row; xqn + kr only ------------------
__global__ __launch_bounds__(256) void ln_kernel(
    const float* __restrict__ x,
    const float* __restrict__ qn_w, const float* __restrict__ qn_b,
    const float* __restrict__ kvn_w, const float* __restrict__ kvn_b,
    const float* __restrict__ k_prime,
    uint16_t* __restrict__ xqn_bf, uint16_t* __restrict__ kr,
    float* __restrict__ krowsq)
{
  const int lane = threadIdx.x & 63, w = threadIdx.x >> 6;
  const int row = blockIdx.x * 4 + w;
  const float4* xr = (const float4*)(x + (size_t)row * 1024);
  float4 v[4];
  float s = 0.f, sq = 0.f;
#pragma unroll
  for (int i = 0; i < 4; i++) {
    v[i] = xr[i * 64 + lane];
    s  += v[i].x + v[i].y + v[i].z + v[i].w;
    sq += v[i].x * v[i].x + v[i].y * v[i].y + v[i].z * v[i].z + v[i].w * v[i].w;
  }
  for (int off = 32; off; off >>= 1) { s += __shfl_xor(s, off); sq += __shfl_xor(sq, off); }
  const float mean = s * (1.f / 1024.f);
  const float rstd = rsqrtf(sq * (1.f / 1024.f) - mean * mean + 1e-5f);

  float ksq = 0.f;
  const size_t o4 = (size_t)row * 256;
#pragma unroll
  for (int i = 0; i < 4; i++) {
    const int idx = i * 64 + lane;
    float4 qw = ((const float4*)qn_w)[idx],  qb4 = ((const float4*)qn_b)[idx];
    float4 kw = ((const float4*)kvn_w)[idx], kb4 = ((const float4*)kvn_b)[idx];
    float4 kp = ((const float4*)k_prime)[idx];
    float xn0 = (v[i].x - mean) * rstd, xn1 = (v[i].y - mean) * rstd;
    float xn2 = (v[i].z - mean) * rstd, xn3 = (v[i].w - mean) * rstd;
    float xq0 = xn0 * qw.x + qb4.x, xq1 = xn1 * qw.y + qb4.y;
    float xq2 = xn2 * qw.z + qb4.z, xq3 = xn3 * qw.w + qb4.w;
    float xk0 = xn0 * kw.x + kb4.x, xk1 = xn1 * kw.y + kb4.y;
    float xk2 = xn2 * kw.z + kb4.z, xk3 = xn3 * kw.w + kb4.w;
    float k0 = xk0 * sigm(kp.x), k1 = xk1 * sigm(kp.y);
    float k2 = xk2 * sigm(kp.z), k3 = xk3 * sigm(kp.w);
    ksq += k0 * k0 + k1 * k1 + k2 * k2 + k3 * k3;
    ((ushort4*)xqn_bf)[o4 + idx] = make_ushort4(f2bf(xq0), f2bf(xq1), f2bf(xq2), f2bf(xq3));
    ((ushort4*)kr)[o4 + idx] = make_ushort4(f2bf(k0), f2bf(k1), f2bf(k2), f2bf(k3));
  }
  for (int off = 32; off; off >>= 1) ksq += __shfl_xor(ksq, off);
  if (lane == 0) krowsq[row] = ksq;   // contention-free per-row store
}

// ---------------- qr GEMM: qr = (xqn @ qW^T + qb) * sig(q_prime); + row norms
__global__ __launch_bounds__(256) void qr_gemm_kernel(
    const uint16_t* __restrict__ xqn_bf, const uint16_t* __restrict__ qWbf,
    const float* __restrict__ qb, const float* __restrict__ q_prime,
    uint16_t* __restrict__ qr, float* __restrict__ qnormsq)
{
  __shared__ uint16_t sA[128 * 64], sB[128 * 64];
  f32x4 acc[4][4];
#pragma unroll
  for (int i = 0; i < 4; i++)
#pragma unroll
    for (int j = 0; j < 4; j++) acc[i][j] = (f32x4)0.0f;

  const int rowBase = blockIdx.y * 128, colBase = blockIdx.x * 128;
  gemm_tile(xqn_bf + (size_t)rowBase * 1024, 1024,
            qWbf + (size_t)colBase * 1024, 1024, 1024, sA, sB, acc);

  const int lane = threadIdx.x & 63, w = threadIdx.x >> 6;
  const int wr = (w >> 1) * 64, wc = (w & 1) * 64;
  float rsq[4][4] = {};
#pragma unroll
  for (int ni = 0; ni < 4; ni++) {
    int gc = colBase + wc + ni * 16 + (lane & 15);
    float scale = sigm(q_prime[gc]);
    float bias = qb[gc];
#pragma unroll
    for (int mi = 0; mi < 4; mi++)
#pragma unroll
      for (int r = 0; r < 4; r++) {
        int gr = rowBase + wr + mi * 16 + (lane >> 4) * 4 + r;
        float val = (acc[mi][ni][r] + bias) * scale;
        qr[(size_t)gr * 1024 + gc] = f2bf(val);
        rsq[mi][r] += val * val;
      }
  }
#pragma unroll
  for (int mi = 0; mi < 4; mi++)
#pragma unroll
    for (int r = 0; r < 4; r++) {
      float t = rsq[mi][r];
      t += __shfl_xor(t, 1); t += __shfl_xor(t, 2);
      t += __shfl_xor(t, 4); t += __shfl_xor(t, 8);
      rsq[mi][r] = t;
    }
  if ((lane & 15) == 0) {
#pragma unroll
    for (int mi = 0; mi < 4; mi++)
#pragma unroll
      for (int r = 0; r < 4; r++)
        atomicAdd(&qnormsq[rowBase + wr + mi * 16 + (lane >> 4) * 4 + r], rsq[mi][r]);
  }
}

// ---------------- bound: Mhat[b] = max||qr|| * max||kr|| / 32 -------------
__global__ void bound_kernel(const float* __restrict__ qnormsq,
                             const float* __restrict__ krowsq, float* __restrict__ MZ)
{
  const int b = blockIdx.x, tid = threadIdx.x, lane = tid & 63, w = tid >> 6;
  float mq = 0.f, mk = 0.f;
  for (int i = tid; i < 2048; i += 256) {
    mq = fmaxf(mq, qnormsq[b * 2048 + i]);
    mk = fmaxf(mk, krowsq[b * 2048 + i]);
  }
  for (int off = 32; off; off >>= 1) {
    mq = fmaxf(mq, __shfl_xor(mq, off));
    mk = fmaxf(mk, __shfl_xor(mk, off));
  }
  __shared__ float rm[4], rk[4];
  if (lane == 0) { rm[w] = mq; rk[w] = mk; }
  __syncthreads();
  if (tid == 0) {
    float qmax = fmaxf(fmaxf(rm[0], rm[1]), fmaxf(rm[2], rm[3]));
    float kmax = fmaxf(fmaxf(rk[0], rk[1]), fmaxf(rk[2], rk[3]));
    MZ[b] = sqrtf(qmax * kmax) * 0.03125f;   // rigorous: s <= ||q||*||k||/32
  }
}

// ---- transpose+scale: vrt[b,h,t] = kr[b,t,h] * gate2[h] (vr eliminated) --
__global__ void transpose_kernel(const uint16_t* __restrict__ kr,
                                 const float* __restrict__ gate2,
                                 uint16_t* __restrict__ vrt)
{
  __shared__ uint16_t t[64 * 72];
  const int b = blockIdx.z;
  const int t0 = blockIdx.x * 64, h0 = blockIdx.y * 64;
  const uint16_t* src = kr + (size_t)b * 2048 * 1024;
#pragma unroll
  for (int p = 0; p < 2; p++) {
    int flat = p * 256 + threadIdx.x;
    int r = flat >> 3, c = (flat & 7) * 8;
    *(uint4*)(&t[r * 72 + c]) = *(const uint4*)(src + (size_t)(t0 + r) * 1024 + h0 + c);
  }
  __syncthreads();
  uint16_t* dst = vrt + (size_t)b * 1024 * 2048;
#pragma unroll
  for (int p = 0; p < 2; p++) {
    int flat = p * 256 + threadIdx.x;
    int oh = flat >> 3, oc = (flat & 7) * 8;
    const float g = gate2[h0 + oh];
    union { uint16_t e[8]; uint4 v; } u;
#pragma unroll
    for (int j = 0; j < 8; j++) u.e[j] = f2bf(bf2f(t[(oc + j) * 72 + oh]) * g);
    *(uint4*)(dst + (size_t)(h0 + oh) * 2048 + t0 + oc) = u.v;
  }
}

// ---------------- scores GEMM: P' = exp(s - Mhat), partial Z --------------
// 1D grid 2048, XCD swizzle: b=lid>>8, c=(lid>>4)&15, r=lid&15 -> XCD=r&7:
// all 16 col-blocks of a qr row-tile land on one XCD -> A reused from L2.
__global__ __launch_bounds__(256) void scores_kernel(
    const uint16_t* __restrict__ qr, const uint16_t* __restrict__ kr,
    const float* __restrict__ MZ,
    uint16_t* __restrict__ scores, float* __restrict__ blockZ)
{
  __shared__ uint16_t sA[128 * 64], sB[128 * 64];
  __shared__ float redz[4];
  const int lid = blockIdx.x;
  const int b = lid >> 8, c = (lid >> 4) & 15, r = lid & 15;
  f32x4 acc[4][4];
#pragma unroll
  for (int i = 0; i < 4; i++)
#pragma unroll
    for (int j = 0; j < 4; j++) acc[i][j] = (f32x4)0.0f;

  const uint16_t* A = qr + (size_t)b * 2048 * 1024 + (size_t)r * 128 * 1024;
  const uint16_t* B = kr + (size_t)b * 2048 * 1024 + (size_t)c * 128 * 1024;
  gemm_tile(A, 1024, B, 1024, 1024, sA, sB, acc);

  const float Mhat = MZ[b];
  const int lane = threadIdx.x & 63, w = threadIdx.x >> 6;
  const int wr = (w >> 1) * 64, wc = (w & 1) * 64;
  uint16_t* S = scores + ((size_t)b << 22);
  const int rb = r * 128 + wr, cb = c * 128 + wc;

  float zt = 0.f;
#pragma unroll
  for (int mi = 0; mi < 4; mi++)
#pragma unroll
    for (int ni = 0; ni < 4; ni++)
#pragma unroll
      for (int rr = 0; rr < 4; rr++) {
        float p = __expf(acc[mi][ni][rr] * 0.03125f - Mhat);
        zt += p;
        S[(size_t)(rb + mi * 16 + (lane >> 4) * 4 + rr) * 2048 + (cb + ni * 16 + (lane & 15))] = f2bf(p);
      }
  for (int off = 32; off; off >>= 1) zt += __shfl_xor(zt, off);
  if (lane == 0) redz[w] = zt;
  __syncthreads();
  if (threadIdx.x == 0) blockZ[lid] = redz[0] + redz[1] + redz[2] + redz[3];
}

// ---------------- Z reduce: per-batch sum of 256 block Z ------------------
__global__ void zreduce_kernel(const float* __restrict__ blockZ, float* __restrict__ MZ)
{
  const int b = blockIdx.x, tid = threadIdx.x, lane = tid & 63, w = tid >> 6;
  float z = blockZ[b * 256 + tid];
  for (int off = 32; off; off >>= 1) z += __shfl_xor(z, off);
  __shared__ float rz[4];
  if (lane == 0) rz[w] = z;
  __syncthreads();
  if (tid == 0) MZ[8 + b] = rz[0] + rz[1] + rz[2] + rz[3];
}

// ---------------- PV GEMM: out = P' @ vrt^T / Z + xqn (bf16 residual) -----
// 1D grid 1024, XCD swizzle: b=lid>>7, c=(lid>>4)&7, r=lid&15 -> XCD=r&7.
__global__ __launch_bounds__(256) void pv_gemm_kernel(
    const uint16_t* __restrict__ P, const uint16_t* __restrict__ vrt,
    const float* __restrict__ MZ, const uint16_t* __restrict__ xqn_bf,
    float* __restrict__ out)
{
  __shared__ uint16_t sA[128 * 64], sB[128 * 64];
  const int lid = blockIdx.x;
  const int b = lid >> 7, c = (lid >> 4) & 7, r = lid & 15;
  f32x4 acc[4][4];
#pragma unroll
  for (int i = 0; i < 4; i++)
#pragma unroll
    for (int j = 0; j < 4; j++) acc[i][j] = (f32x4)0.0f;

  const uint16_t* A = P + ((size_t)b << 22) + (size_t)r * 128 * 2048;
  const uint16_t* B = vrt + (size_t)b * 1024 * 2048 + (size_t)c * 128 * 2048;
  gemm_tile(A, 2048, B, 2048, 2048, sA, sB, acc);

  const float invZ = 1.0f / MZ[8 + b];
  const int lane = threadIdx.x & 63, w = threadIdx.x >> 6;
  const int wr = (w >> 1) * 64, wc = (w & 1) * 64;
  const int rb = r * 128 + wr, cb = c * 128 + wc;
#pragma unroll
  for (int mi = 0; mi < 4; mi++)
#pragma unroll
    for (int ni = 0; ni < 4; ni++)
#pragma unroll
      for (int rr = 0; rr < 4; rr++) {
        int gr = rb + mi * 16 + (lane >> 4) * 4 + rr;
        int gc = cb + ni * 16 + (lane & 15);
        size_t o = ((size_t)b * 2048 + gr) * 1024 + gc;
        out[o] = acc[mi][ni][rr] * invZ + bf2f(xqn_bf[o]);
      }
}

extern "C" void kernel_launch(void* const* d_in, const int* in_sizes, int n_in,
                              void* d_out, int out_size, void* d_ws, size_t ws_size,
                              hipStream_t stream) {
  const float* x       = (const float*)d_in[0];
  const float* qn_w    = (const float*)d_in[1];
  const float* qn_b    = (const float*)d_in[2];
  const float* kvn_w   = (const float*)d_in[3];
  const float* kvn_b   = (const float*)d_in[4];
  const float* q_prime = (const float*)d_in[5];
  const float* k_prime = (const float*)d_in[6];
  const float* v_prime = (const float*)d_in[7];
  const float* qW      = (const float*)d_in[8];
  const float* qb      = (const float*)d_in[9];
  const float* v1W     = (const float*)d_in[10];
  const float* v1b     = (const float*)d_in[11];
  const float* v2W     = (const float*)d_in[12];
  const float* v2b     = (const float*)d_in[13];
  float* out = (float*)d_out;

  const size_t BS = 16384, H = 1024;
  char* ws = (char*)d_ws;
  size_t off = 0;
  auto alloc = [&](size_t bytes) -> char* {
    char* p = ws + off;
    off = (off + bytes + 255) & ~(size_t)255;
    return p;
  };
  float*    gate2   = (float*)alloc(H * 4);
  float*    MZ      = (float*)alloc(16 * 4);        // [0..7]=Mhat, [8..15]=Z
  float*    blockZ  = (float*)alloc(2048 * 4);
  float*    qnormsq = (float*)alloc(16384 * 4);     // atomicAdd target (memset)
  float*    krowsq  = (float*)alloc(16384 * 4);     // plain per-row stores
  uint16_t* qWbf    = (uint16_t*)alloc(H * H * 2);
  uint16_t* xqn_bf  = (uint16_t*)alloc(BS * H * 2); // lives to the end
  uint16_t* kr      = (uint16_t*)alloc(BS * H * 2);
  uint16_t* scores  = (uint16_t*)alloc(BS * H * 2 * 2);  // 64 MB
  uint16_t* vrt     = (uint16_t*)alloc(BS * H * 2);
  uint16_t* qr      = (uint16_t*)alloc(BS * H * 2);

  hipMemsetAsync(qnormsq, 0, 16384 * 4, stream);
  gate_kernel<<<256, 256, 0, stream>>>(v_prime, v1W, v1b, v2W, v2b, k_prime, gate2);
  cvt_kernel<<<1024, 256, 0, stream>>>(qW, qWbf);
  ln_kernel<<<4096, 256, 0, stream>>>(x, qn_w, qn_b, kvn_w, kvn_b, k_prime,
                                      xqn_bf, kr, krowsq);
  qr_gemm_kernel<<<dim3(8, 128), 256, 0, stream>>>(xqn_bf, qWbf, qb, q_prime, qr, qnormsq);
  transpose_kernel<<<dim3(32, 16, 8), 256, 0, stream>>>(kr, gate2, vrt);
  bound_kernel<<<8, 256, 0, stream>>>(qnormsq, krowsq, MZ);
  scores_kernel<<<2048, 256, 0, stream>>>(qr, kr, MZ, scores, blockZ);
  zreduce_kernel<<<8, 256, 0, stream>>>(blockZ, MZ);
  pv_gemm_kernel<<<1024, 256, 0, stream>>>(scores, vrt, MZ, xqn_bf, out);
}